// Round 5
// baseline (134.519 us; speedup 1.0000x reference)
//
#include <hip/hip_runtime.h>
#include <hip/hip_bf16.h>
#include <math.h>

#define NV 50257
#define NE 256
#define NC 48
#define NB 64
#define NT 1024
#define NCHUNK 64          // 63 chunks of 16 factors + 1 chunk of 15 = 1023
#define L2E 1.44269504088896340736f
#define LN2 0.69314718055994530942f

typedef __attribute__((ext_vector_type(8)))  short bf16x8;
typedef __attribute__((ext_vector_type(16))) float f32x16;

__device__ __forceinline__ unsigned pk_bf16(float lo, float hi) {
    unsigned r;
    asm("v_cvt_pk_bf16_f32 %0, %1, %2" : "=v"(r) : "v"(lo), "v"(hi));
    return r;
}
__device__ __forceinline__ bf16x8 mk8(unsigned u0, unsigned u1, unsigned u2, unsigned u3) {
    union { unsigned u[4]; bf16x8 v; } t;
    t.u[0] = u0; t.u[1] = u1; t.u[2] = u2; t.u[3] = u3;
    return t.v;
}
__device__ __forceinline__ float readlane_f(float v, int l) {
    return __uint_as_float(__builtin_amdgcn_readlane(__float_as_uint(v), l));
}

// ---------------------------------------------------------------------------
// Kernel 1: logits[b,t,c] = emb[x[b,t]] . fc_w[c] + fc_b[c]   (pure GEMM)
// 256 blocks x 128 thr; 64 tokens/block; 2 waves split K (0-127 / 128-255);
// w in LDS (stride 260 -> cg-group reads 2-way = free); emb dbuf in registers.
// Each lane: 4 consecutive tokens x 12 classes.
// ---------------------------------------------------------------------------
#define PREF(BUF, CH)                                                     \
  { _Pragma("unroll")                                                     \
    for (int i_ = 0; i_ < 4; ++i_) {                                      \
        BUF[2*i_]   = r4[i_][(CH)*2];                                     \
        BUF[2*i_+1] = r4[i_][(CH)*2+1];                                   \
    } }

#define COMP(BUF, CH)                                                     \
  { _Pragma("unroll")                                                     \
    for (int jc_ = 0; jc_ < 12; ++jc_) {                                  \
        const float* wp_ = ws + (cg*12+jc_)*260 + wv*128 + (CH)*8;        \
        float4 w0_ = *(const float4*)(wp_);                               \
        float4 w1_ = *(const float4*)(wp_+4);                             \
        _Pragma("unroll")                                                 \
        for (int i_ = 0; i_ < 4; ++i_) {                                  \
            acc[i_][jc_] = fmaf(BUF[2*i_].x,   w0_.x, acc[i_][jc_]);      \
            acc[i_][jc_] = fmaf(BUF[2*i_].y,   w0_.y, acc[i_][jc_]);      \
            acc[i_][jc_] = fmaf(BUF[2*i_].z,   w0_.z, acc[i_][jc_]);      \
            acc[i_][jc_] = fmaf(BUF[2*i_].w,   w0_.w, acc[i_][jc_]);      \
            acc[i_][jc_] = fmaf(BUF[2*i_+1].x, w1_.x, acc[i_][jc_]);      \
            acc[i_][jc_] = fmaf(BUF[2*i_+1].y, w1_.y, acc[i_][jc_]);      \
            acc[i_][jc_] = fmaf(BUF[2*i_+1].z, w1_.z, acc[i_][jc_]);      \
            acc[i_][jc_] = fmaf(BUF[2*i_+1].w, w1_.w, acc[i_][jc_]);      \
        } } }

__global__ __launch_bounds__(128) void logits_kernel(
    const int* __restrict__ x, const float* __restrict__ emb,
    const float* __restrict__ w, const float* __restrict__ bias,
    float* __restrict__ out)
{
    __shared__ __align__(16) float ws[NC * 260];
    __shared__ __align__(16) float red[64 * NC];
    __shared__ float bsh[NC];

    const int tid = threadIdx.x;
    const int base = blockIdx.x * 64;

    // stage w with leading-dim pad 260
#pragma unroll
    for (int i = 0; i < 24; ++i) {
        const int q = i * 128 + tid;       // float4-quad index, 0..3071
        const int c = q >> 6, kq = q & 63;
        float4 v = ((const float4*)w)[q];
        *(float4*)(ws + c * 260 + 4 * kq) = v;
    }
    if (tid < NC) bsh[tid] = bias[tid];

    const int wv = tid >> 6;               // k-half
    const int lane = tid & 63;
    const int tg = lane >> 2, cg = lane & 3;
    const int tok0 = base + tg * 4;

    const float4* r4[4];
#pragma unroll
    for (int i = 0; i < 4; ++i)
        r4[i] = (const float4*)(emb + (size_t)x[tok0 + i] * NE) + wv * 32;

    float acc[4][12];
#pragma unroll
    for (int i = 0; i < 4; ++i)
#pragma unroll
        for (int j = 0; j < 12; ++j) acc[i][j] = 0.f;

    __syncthreads();

    float4 cur[8], nxt[8];
    PREF(cur, 0);
#pragma unroll 1
    for (int chp = 0; chp < 8; ++chp) {
        const int ch0 = 2 * chp;
        PREF(nxt, ch0 + 1);
        COMP(cur, ch0);
        if (chp < 7) PREF(cur, ch0 + 2);
        COMP(nxt, ch0 + 1);
    }

    // k-split reduction via LDS
    if (wv == 1) {
#pragma unroll
        for (int i = 0; i < 4; ++i) {
            float* rp = red + (tg * 4 + i) * NC + cg * 12;
            *(float4*)(rp + 0) = make_float4(acc[i][0], acc[i][1], acc[i][2], acc[i][3]);
            *(float4*)(rp + 4) = make_float4(acc[i][4], acc[i][5], acc[i][6], acc[i][7]);
            *(float4*)(rp + 8) = make_float4(acc[i][8], acc[i][9], acc[i][10], acc[i][11]);
        }
    }
    __syncthreads();
    if (wv == 0) {
#pragma unroll
        for (int i = 0; i < 4; ++i) {
            const float* rp = red + (tg * 4 + i) * NC + cg * 12;
            float4 p0 = *(const float4*)(rp + 0);
            float4 p1 = *(const float4*)(rp + 4);
            float4 p2 = *(const float4*)(rp + 8);
            float* op = out + (size_t)(base + tg * 4 + i) * NC + cg * 12;
            *(float4*)(op + 0) = make_float4(acc[i][0] + p0.x + bsh[cg*12+0], acc[i][1] + p0.y + bsh[cg*12+1],
                                             acc[i][2] + p0.z + bsh[cg*12+2], acc[i][3] + p0.w + bsh[cg*12+3]);
            *(float4*)(op + 4) = make_float4(acc[i][4] + p1.x + bsh[cg*12+4], acc[i][5] + p1.y + bsh[cg*12+5],
                                             acc[i][6] + p1.z + bsh[cg*12+6], acc[i][7] + p1.w + bsh[cg*12+7]);
            *(float4*)(op + 8) = make_float4(acc[i][8] + p2.x + bsh[cg*12+8], acc[i][9] + p2.y + bsh[cg*12+9],
                                             acc[i][10] + p2.z + bsh[cg*12+10], acc[i][11] + p2.w + bsh[cg*12+11]);
        }
    }
}

// ---------------------------------------------------------------------------
// Kernel 2: chunked matrix scan, 64 chunks x <=16 factors per batch.
// C_j = M_{t0+CL} ... M_{t0+1},  M_t = diag(E_t) P^T,  E from logits on the fly.
// W_1 = P^T; 15 steps of W <- P^T (diag(E) W); final row-scale by E_{t0+CL}.
// All fragments in NAMED registers.
// ---------------------------------------------------------------------------
__device__ __forceinline__ bf16x8 mkA(const float* __restrict__ trans, int r, int h, int kf) {
    unsigned u[4];
#pragma unroll
    for (int p = 0; p < 4; ++p) {
        const int i0 = 2 * p;
        const int k0 = 16 * kf + 4 * h + (i0 & 3) + 8 * (i0 >> 2);
        const int k1 = k0 + 1;
        float v0 = (r < NC && k0 < NC) ? exp2f(trans[k0 * NC + r] * L2E) : 0.f;
        float v1 = (r < NC && k1 < NC) ? exp2f(trans[k1 * NC + r] * L2E) : 0.f;
        u[p] = pk_bf16(v0, v1);
    }
    return mk8(u[0], u[1], u[2], u[3]);
}

__device__ __forceinline__ f32x16 mkW(const float* __restrict__ trans, int rt, int ct, int h, int l31) {
    f32x16 r;
#pragma unroll
    for (int reg = 0; reg < 16; ++reg) {
        const int rw = 32 * rt + (reg & 3) + 8 * (reg >> 2) + 4 * h;
        const int cc = 32 * ct + l31;
        r[reg] = (rw < NC && cc < NC) ? exp2f(trans[cc * NC + rw] * L2E) : 0.f;
    }
    return r;
}

__device__ __forceinline__ f32x16 mm4(bf16x8 a0, bf16x8 a1, bf16x8 a2, bf16x8 a3,
                                      bf16x8 b0, bf16x8 b1, bf16x8 b2, bf16x8 b3) {
    f32x16 z;
#pragma unroll
    for (int i = 0; i < 16; ++i) z[i] = 0.f;
    f32x16 d = __builtin_amdgcn_mfma_f32_32x32x16_bf16(a0, b0, z, 0, 0, 0);
    d = __builtin_amdgcn_mfma_f32_32x32x16_bf16(a1, b1, d, 0, 0, 0);
    d = __builtin_amdgcn_mfma_f32_32x32x16_bf16(a2, b2, d, 0, 0, 0);
    d = __builtin_amdgcn_mfma_f32_32x32x16_bf16(a3, b3, d, 0, 0, 0);
    return d;
}

__device__ __forceinline__ void scaleRows(f32x16& A, const float* ef, int rt, int h) {
#pragma unroll
    for (int g = 0; g < 4; ++g) {
        float4 e = *(const float4*)(ef + 32 * rt + 8 * g + 4 * h);
        A[4*g+0] *= e.x; A[4*g+1] *= e.y; A[4*g+2] *= e.z; A[4*g+3] *= e.w;
    }
}

__device__ __forceinline__ void storeQ(unsigned* __restrict__ cbase, const f32x16& A,
                                       float inv, int rt, int ct, int h, int l31) {
#pragma unroll
    for (int g = 0; g < 4; ++g)
#pragma unroll
        for (int pp = 0; pp < 2; ++pp) {
            const int reg = 4 * g + 2 * pp;
            unsigned u = pk_bf16(A[reg] * inv, A[reg + 1] * inv);
            const int rw = 32 * rt + 2 * pp + 8 * g + 4 * h;
            cbase[(rw >> 1) * 64 + 32 * ct + l31] = u;
        }
}

#define MKB(BD0, BD1, S0, S1, q, eo)                                      \
  {                                                                       \
    float4 _e0 = *(const float4*)(ep + (eo));                             \
    float4 _e1 = *(const float4*)(ep + (eo) + 8);                         \
    unsigned _u0 = pk_bf16(S0[(q)+0]*_e0.x, S0[(q)+1]*_e0.y);             \
    unsigned _u1 = pk_bf16(S0[(q)+2]*_e0.z, S0[(q)+3]*_e0.w);             \
    unsigned _u2 = pk_bf16(S0[(q)+4]*_e1.x, S0[(q)+5]*_e1.y);             \
    unsigned _u3 = pk_bf16(S0[(q)+6]*_e1.z, S0[(q)+7]*_e1.w);             \
    BD0 = mk8(_u0, _u1, _u2, _u3);                                        \
    _u0 = pk_bf16(S1[(q)+0]*_e0.x, S1[(q)+1]*_e0.y);                      \
    _u1 = pk_bf16(S1[(q)+2]*_e0.z, S1[(q)+3]*_e0.w);                      \
    _u2 = pk_bf16(S1[(q)+4]*_e1.x, S1[(q)+5]*_e1.y);                      \
    _u3 = pk_bf16(S1[(q)+6]*_e1.z, S1[(q)+7]*_e1.w);                      \
    BD1 = mk8(_u0, _u1, _u2, _u3);                                        \
  }

__global__ __launch_bounds__(64) void scan_kernel(
    const float* __restrict__ trans, const float* __restrict__ logits,
    unsigned* __restrict__ Cpk, float* __restrict__ S2tab)
{
    const int j = blockIdx.x;          // chunk
    const int b = blockIdx.y;          // batch
    const int lane = threadIdx.x;
    const int h = lane >> 5, l31 = lane & 31;
    const int t0 = j * 16;
    const int cl = (j == NCHUNK - 1) ? 15 : 16;

    __shared__ __align__(16) float El[16 * 64];

    // ---- stage E rows from logits: 4 lanes per row, row-max normalize ----
    const int row = lane >> 2, cs = lane & 3;
    float s2v = 0.f;
    {
        float e[12];
        float mloc = -3.0e38f;
        if (row < cl) {
            const float* lr = logits + ((size_t)b * NT + t0 + 1 + row) * NC + cs * 12;
            float4 v0 = *(const float4*)(lr + 0);
            float4 v1 = *(const float4*)(lr + 4);
            float4 v2 = *(const float4*)(lr + 8);
            e[0]=v0.x; e[1]=v0.y; e[2]=v0.z;  e[3]=v0.w;
            e[4]=v1.x; e[5]=v1.y; e[6]=v1.z;  e[7]=v1.w;
            e[8]=v2.x; e[9]=v2.y; e[10]=v2.z; e[11]=v2.w;
#pragma unroll
            for (int q = 0; q < 12; ++q) mloc = fmaxf(mloc, e[q]);
        }
        mloc = fmaxf(mloc, __shfl_xor(mloc, 1));
        mloc = fmaxf(mloc, __shfl_xor(mloc, 2));
        const float m2 = mloc * L2E;
        float* er = El + row * 64;
        if (row < cl) {
#pragma unroll
            for (int q = 0; q < 12; ++q) er[cs * 12 + q] = exp2f(e[q] * L2E - m2);
            if (cs == 0) s2v = m2;
        }
        if (cs == 3) {   // zero-pad cols 48..63 (every row, incl. unused)
            *(float4*)(er + 48) = make_float4(0.f, 0.f, 0.f, 0.f);
            *(float4*)(er + 52) = make_float4(0.f, 0.f, 0.f, 0.f);
            *(float4*)(er + 56) = make_float4(0.f, 0.f, 0.f, 0.f);
            *(float4*)(er + 60) = make_float4(0.f, 0.f, 0.f, 0.f);
        }
    }
    __syncthreads();

    // ---- constant A = P^T frags; W init = P^T in D-layout ----
    bf16x8 A00 = mkA(trans, l31,      h, 0), A01 = mkA(trans, l31,      h, 1),
           A02 = mkA(trans, l31,      h, 2), A03 = mkA(trans, l31,      h, 3);
    bf16x8 A10 = mkA(trans, l31 + 32, h, 0), A11 = mkA(trans, l31 + 32, h, 1),
           A12 = mkA(trans, l31 + 32, h, 2), A13 = mkA(trans, l31 + 32, h, 3);

    f32x16 acc00 = mkW(trans, 0, 0, h, l31), acc01 = mkW(trans, 0, 1, h, l31),
           acc10 = mkW(trans, 1, 0, h, l31), acc11 = mkW(trans, 1, 1, h, l31);

    const int nst = cl - 1;
#pragma unroll 1
    for (int s = 1; s <= nst; ++s) {
        const float* ep = El + (s - 1) * 64;
        bf16x8 B00, B01, B10, B11, B20, B21, B30, B31;
        MKB(B00, B01, acc00, acc01, 0, 0 * 16 + 4 * h);
        MKB(B10, B11, acc00, acc01, 8, 1 * 16 + 4 * h);
        MKB(B20, B21, acc10, acc11, 0, 2 * 16 + 4 * h);
        MKB(B30, B31, acc10, acc11, 8, 3 * 16 + 4 * h);
        f32x16 n00 = mm4(A00, A01, A02, A03, B00, B10, B20, B30);
        f32x16 n01 = mm4(A00, A01, A02, A03, B01, B11, B21, B31);
        f32x16 n10 = mm4(A10, A11, A12, A13, B00, B10, B20, B30);
        f32x16 n11 = mm4(A10, A11, A12, A13, B01, B11, B21, B31);
        acc00 = n00; acc01 = n01; acc10 = n10; acc11 = n11;
    }

    // final: row-scale by E_{t0+cl} (row index nst)
    const float* ef = El + nst * 64;
    scaleRows(acc00, ef, 0, h); scaleRows(acc01, ef, 0, h);
    scaleRows(acc10, ef, 1, h); scaleRows(acc11, ef, 1, h);

    // max-normalize + bookkeeping
    float m = acc00[0];
#pragma unroll
    for (int r = 0; r < 16; ++r) {
        m = fmaxf(m, acc00[r]); m = fmaxf(m, acc01[r]);
        m = fmaxf(m, acc10[r]); m = fmaxf(m, acc11[r]);
    }
#pragma unroll
    for (int o = 32; o; o >>= 1) m = fmaxf(m, __shfl_xor(m, o));
    const float inv = 1.f / m;

    float sv = s2v;
#pragma unroll
    for (int o = 32; o; o >>= 1) sv += __shfl_xor(sv, o);

    unsigned* cbase = Cpk + (((size_t)b * NCHUNK + j) << 11);
    storeQ(cbase, acc00, inv, 0, 0, h, l31);
    storeQ(cbase, acc01, inv, 0, 1, h, l31);
    storeQ(cbase, acc10, inv, 1, 0, h, l31);
    storeQ(cbase, acc11, inv, 1, 1, h, l31);

    if (lane == 0) S2tab[b * NCHUNK + j] = sv + log2f(m);
}

// ---------------------------------------------------------------------------
// Kernel 3: combine — a <- C_j a over 64 chunks (48-col readlane matvec,
// dbuf loads, rescale every 4), plus numerator and final log_z.
// ---------------------------------------------------------------------------
__device__ __forceinline__ void comb_load(const unsigned* __restrict__ cb, int k,
                                          uint4* __restrict__ buf) {
    const uint4* p = (const uint4*)(cb + (size_t)k * 2048);
#pragma unroll
    for (int q = 0; q < 12; ++q) buf[q] = p[q];
}

__device__ __forceinline__ void comb_step(const uint4* __restrict__ buf,
                                          float& a, unsigned sh) {
    float sreg[48];
#pragma unroll
    for (int c = 0; c < 48; ++c) sreg[c] = readlane_f(a, c);
    __builtin_amdgcn_sched_barrier(0);
    float a0 = 0.f, a1 = 0.f, a2 = 0.f, a3 = 0.f;
#pragma unroll
    for (int q = 0; q < 12; ++q) {
        uint4 u = buf[q];
        a0 = fmaf(__uint_as_float((u.x << sh) & 0xffff0000u), sreg[4*q+0], a0);
        a1 = fmaf(__uint_as_float((u.y << sh) & 0xffff0000u), sreg[4*q+1], a1);
        a2 = fmaf(__uint_as_float((u.z << sh) & 0xffff0000u), sreg[4*q+2], a2);
        a3 = fmaf(__uint_as_float((u.w << sh) & 0xffff0000u), sreg[4*q+3], a3);
    }
    a = (a0 + a1) + (a2 + a3);
}

__global__ __launch_bounds__(64) void combine_kernel(
    const int* __restrict__ labels, const float* __restrict__ logits,
    const float* __restrict__ start_t, const float* __restrict__ end_t,
    const float* __restrict__ trans, const unsigned* __restrict__ Cpk,
    const float* __restrict__ S2tab, float* __restrict__ out_scalar)
{
    const int b = blockIdx.x;
    const int lane = threadIdx.x;
    const int* __restrict__ lab = labels + b * NT;
    const float* __restrict__ lgp = logits + (size_t)b * NT * NC;

    // numerator
    float nsum = 0.f;
#pragma unroll
    for (int i = 0; i < NT / 64; ++i) {
        const int t = i * 64 + lane;
        const int l = lab[t];
        nsum += lgp[t * NC + l];
        if (t > 0) nsum += trans[lab[t - 1] * NC + l];
    }
#pragma unroll
    for (int o = 32; o; o >>= 1) nsum += __shfl_xor(nsum, o);

    // forward: a0, then 64 chunk matvecs
    float a = (lane < NC) ? exp2f((start_t[lane] + lgp[lane]) * L2E) : 0.f;
    float S2 = 0.f;
    const unsigned sh = (lane & 1) ? 0u : 16u;
    const unsigned* cb = Cpk + (((size_t)b * NCHUNK) << 11) + (lane >> 1) * 64;

    uint4 bufA[12], bufB[12];
    comb_load(cb, 0, bufA);
#pragma unroll 1
    for (int k = 0; k < NCHUNK; k += 2) {
        if (k + 1 < NCHUNK) comb_load(cb, k + 1, bufB);
        comb_step(bufA, a, sh);
        if (k + 2 < NCHUNK) comb_load(cb, k + 2, bufA);
        comb_step(bufB, a, sh);
        if ((k & 2) != 0) {   // rescale every 4 chunk-steps
            float mm = a;
#pragma unroll
            for (int o = 32; o; o >>= 1) mm = fmaxf(mm, __shfl_xor(mm, o));
            a *= 1.f / mm;
            S2 += log2f(mm);
        }
    }

    float pe = (lane < NC) ? a * exp2f(end_t[lane] * L2E) : 0.f;
#pragma unroll
    for (int o = 32; o; o >>= 1) pe += __shfl_xor(pe, o);
    float s2k = S2tab[b * NCHUNK + lane];   // NCHUNK == 64 == wave
#pragma unroll
    for (int o = 32; o; o >>= 1) s2k += __shfl_xor(s2k, o);

    if (lane == 0) {
        const float logz = (S2 + s2k + log2f(pe)) * LN2;
        const float numer = nsum + start_t[lab[0]] + end_t[lab[NT - 1]];
        atomicAdd(out_scalar, logz - numer);
    }
}

// ---------------------------------------------------------------------------
extern "C" void kernel_launch(void* const* d_in, const int* in_sizes, int n_in,
                              void* d_out, int out_size, void* d_ws, size_t ws_size,
                              hipStream_t stream) {
    const int*   x       = (const int*)d_in[0];
    const int*   labels  = (const int*)d_in[1];
    const float* emb     = (const float*)d_in[2];
    const float* fc_w    = (const float*)d_in[3];
    const float* fc_b    = (const float*)d_in[4];
    const float* start_t = (const float*)d_in[5];
    const float* end_t   = (const float*)d_in[6];
    const float* trans   = (const float*)d_in[7];

    float* out = (float*)d_out;
    float* out_scalar = out + (size_t)NB * NT * NC;

    // workspace carve: Cpk 32 MB + S2tab 16 KB
    char* ws = (char*)d_ws;
    constexpr size_t CP_BYTES = (size_t)NB * NCHUNK * 2048 * 4;
    unsigned* Cpk   = (unsigned*)ws;
    float*    S2tab = (float*)(ws + CP_BYTES);

    (void)hipMemsetAsync(out_scalar, 0, sizeof(float), stream);
    logits_kernel<<<NB * NT / 64, 128, 0, stream>>>(x, emb, fc_w, fc_b, out);
    scan_kernel<<<dim3(NCHUNK, NB), 64, 0, stream>>>(trans, out, Cpk, S2tab);
    combine_kernel<<<NB, 64, 0, stream>>>(labels, out, start_t, end_t, trans, Cpk, S2tab, out_scalar);
}

// Round 6
// 93.756 us; speedup vs baseline: 1.4348x; 1.4348x over previous
//
#include <hip/hip_runtime.h>
#include <hip/hip_bf16.h>
#include <math.h>

#define NV 50257
#define NE 256
#define NC 48
#define NB 64
#define NT 1024
#define NCHUNK 32          // 31 chunks x 32 factors + 1 chunk x 31 = 1023
#define ELD 68             // El row stride (floats): bank-shift 4, float4-aligned
#define L2E 1.44269504088896340736f
#define LN2 0.69314718055994530942f

typedef __attribute__((ext_vector_type(8)))  short bf16x8;
typedef __attribute__((ext_vector_type(16))) float f32x16;

__device__ __forceinline__ unsigned pk_bf16(float lo, float hi) {
    unsigned r;
    asm("v_cvt_pk_bf16_f32 %0, %1, %2" : "=v"(r) : "v"(lo), "v"(hi));
    return r;
}
__device__ __forceinline__ bf16x8 mk8(unsigned u0, unsigned u1, unsigned u2, unsigned u3) {
    union { unsigned u[4]; bf16x8 v; } t;
    t.u[0] = u0; t.u[1] = u1; t.u[2] = u2; t.u[3] = u3;
    return t.v;
}

// ---------------------------------------------------------------------------
// Kernel 1: logits[b,t,c] = emb[x[b,t]] . fc_w[c] + fc_b[c]   (pure GEMM)
// ---------------------------------------------------------------------------
#define PREF(BUF, CH)                                                     \
  { _Pragma("unroll")                                                     \
    for (int i_ = 0; i_ < 4; ++i_) {                                      \
        BUF[2*i_]   = r4[i_][(CH)*2];                                     \
        BUF[2*i_+1] = r4[i_][(CH)*2+1];                                   \
    } }

#define COMP(BUF, CH)                                                     \
  { _Pragma("unroll")                                                     \
    for (int jc_ = 0; jc_ < 12; ++jc_) {                                  \
        const float* wp_ = ws + (cg*12+jc_)*260 + wv*128 + (CH)*8;        \
        float4 w0_ = *(const float4*)(wp_);                               \
        float4 w1_ = *(const float4*)(wp_+4);                             \
        _Pragma("unroll")                                                 \
        for (int i_ = 0; i_ < 4; ++i_) {                                  \
            acc[i_][jc_] = fmaf(BUF[2*i_].x,   w0_.x, acc[i_][jc_]);      \
            acc[i_][jc_] = fmaf(BUF[2*i_].y,   w0_.y, acc[i_][jc_]);      \
            acc[i_][jc_] = fmaf(BUF[2*i_].z,   w0_.z, acc[i_][jc_]);      \
            acc[i_][jc_] = fmaf(BUF[2*i_].w,   w0_.w, acc[i_][jc_]);      \
            acc[i_][jc_] = fmaf(BUF[2*i_+1].x, w1_.x, acc[i_][jc_]);      \
            acc[i_][jc_] = fmaf(BUF[2*i_+1].y, w1_.y, acc[i_][jc_]);      \
            acc[i_][jc_] = fmaf(BUF[2*i_+1].z, w1_.z, acc[i_][jc_]);      \
            acc[i_][jc_] = fmaf(BUF[2*i_+1].w, w1_.w, acc[i_][jc_]);      \
        } } }

__global__ __launch_bounds__(128) void logits_kernel(
    const int* __restrict__ x, const float* __restrict__ emb,
    const float* __restrict__ w, const float* __restrict__ bias,
    float* __restrict__ out)
{
    __shared__ __align__(16) float ws[NC * 260];
    __shared__ __align__(16) float red[64 * NC];
    __shared__ float bsh[NC];

    const int tid = threadIdx.x;
    const int base = blockIdx.x * 64;

#pragma unroll
    for (int i = 0; i < 24; ++i) {
        const int q = i * 128 + tid;
        const int c = q >> 6, kq = q & 63;
        float4 v = ((const float4*)w)[q];
        *(float4*)(ws + c * 260 + 4 * kq) = v;
    }
    if (tid < NC) bsh[tid] = bias[tid];

    const int wv = tid >> 6;
    const int lane = tid & 63;
    const int tg = lane >> 2, cg = lane & 3;
    const int tok0 = base + tg * 4;

    const float4* r4[4];
#pragma unroll
    for (int i = 0; i < 4; ++i)
        r4[i] = (const float4*)(emb + (size_t)x[tok0 + i] * NE) + wv * 32;

    float acc[4][12];
#pragma unroll
    for (int i = 0; i < 4; ++i)
#pragma unroll
        for (int j = 0; j < 12; ++j) acc[i][j] = 0.f;

    __syncthreads();

    float4 cur[8], nxt[8];
    PREF(cur, 0);
#pragma unroll 1
    for (int chp = 0; chp < 8; ++chp) {
        const int ch0 = 2 * chp;
        PREF(nxt, ch0 + 1);
        COMP(cur, ch0);
        if (chp < 7) PREF(cur, ch0 + 2);
        COMP(nxt, ch0 + 1);
    }

    if (wv == 1) {
#pragma unroll
        for (int i = 0; i < 4; ++i) {
            float* rp = red + (tg * 4 + i) * NC + cg * 12;
            *(float4*)(rp + 0) = make_float4(acc[i][0], acc[i][1], acc[i][2], acc[i][3]);
            *(float4*)(rp + 4) = make_float4(acc[i][4], acc[i][5], acc[i][6], acc[i][7]);
            *(float4*)(rp + 8) = make_float4(acc[i][8], acc[i][9], acc[i][10], acc[i][11]);
        }
    }
    __syncthreads();
    if (wv == 0) {
#pragma unroll
        for (int i = 0; i < 4; ++i) {
            const float* rp = red + (tg * 4 + i) * NC + cg * 12;
            float4 p0 = *(const float4*)(rp + 0);
            float4 p1 = *(const float4*)(rp + 4);
            float4 p2 = *(const float4*)(rp + 8);
            float* op = out + (size_t)(base + tg * 4 + i) * NC + cg * 12;
            *(float4*)(op + 0) = make_float4(acc[i][0] + p0.x + bsh[cg*12+0], acc[i][1] + p0.y + bsh[cg*12+1],
                                             acc[i][2] + p0.z + bsh[cg*12+2], acc[i][3] + p0.w + bsh[cg*12+3]);
            *(float4*)(op + 4) = make_float4(acc[i][4] + p1.x + bsh[cg*12+4], acc[i][5] + p1.y + bsh[cg*12+5],
                                             acc[i][6] + p1.z + bsh[cg*12+6], acc[i][7] + p1.w + bsh[cg*12+7]);
            *(float4*)(op + 8) = make_float4(acc[i][8] + p2.x + bsh[cg*12+8], acc[i][9] + p2.y + bsh[cg*12+9],
                                             acc[i][10] + p2.z + bsh[cg*12+10], acc[i][11] + p2.w + bsh[cg*12+11]);
        }
    }
}

// ---------------------------------------------------------------------------
// Kernel 2: chunked matrix scan — COLUMN-SPLIT: block = 2 waves = 1 chunk,
// each wave owns 32 columns of the 64x64 (48-padded) product. Per-wave live
// set ~110 VGPRs -> arch-VGPR resident, no AGPR round-trips in the chain.
// ---------------------------------------------------------------------------
__device__ __forceinline__ bf16x8 mkA(const float* __restrict__ trans, int r, int h, int kf) {
    unsigned u[4];
#pragma unroll
    for (int p = 0; p < 4; ++p) {
        const int i0 = 2 * p;
        const int k0 = 16 * kf + 4 * h + (i0 & 3) + 8 * (i0 >> 2);
        const int k1 = k0 + 1;
        float v0 = (r < NC && k0 < NC) ? exp2f(trans[k0 * NC + r] * L2E) : 0.f;
        float v1 = (r < NC && k1 < NC) ? exp2f(trans[k1 * NC + r] * L2E) : 0.f;
        u[p] = pk_bf16(v0, v1);
    }
    return mk8(u[0], u[1], u[2], u[3]);
}

__device__ __forceinline__ f32x16 mkW(const float* __restrict__ trans, int rt, int ct, int h, int l31) {
    f32x16 r;
#pragma unroll
    for (int reg = 0; reg < 16; ++reg) {
        const int rw = 32 * rt + (reg & 3) + 8 * (reg >> 2) + 4 * h;
        const int cc = 32 * ct + l31;
        r[reg] = (rw < NC && cc < NC) ? exp2f(trans[cc * NC + rw] * L2E) : 0.f;
    }
    return r;
}

__device__ __forceinline__ f32x16 mm4(bf16x8 a0, bf16x8 a1, bf16x8 a2, bf16x8 a3,
                                      bf16x8 b0, bf16x8 b1, bf16x8 b2, bf16x8 b3) {
    f32x16 z;
#pragma unroll
    for (int i = 0; i < 16; ++i) z[i] = 0.f;
    f32x16 d = __builtin_amdgcn_mfma_f32_32x32x16_bf16(a0, b0, z, 0, 0, 0);
    d = __builtin_amdgcn_mfma_f32_32x32x16_bf16(a1, b1, d, 0, 0, 0);
    d = __builtin_amdgcn_mfma_f32_32x32x16_bf16(a2, b2, d, 0, 0, 0);
    d = __builtin_amdgcn_mfma_f32_32x32x16_bf16(a3, b3, d, 0, 0, 0);
    return d;
}

__device__ __forceinline__ void scaleRows(f32x16& A, const float* ef, int rt, int h) {
#pragma unroll
    for (int g = 0; g < 4; ++g) {
        float4 e = *(const float4*)(ef + 32 * rt + 8 * g + 4 * h);
        A[4*g+0] *= e.x; A[4*g+1] *= e.y; A[4*g+2] *= e.z; A[4*g+3] *= e.w;
    }
}

__device__ __forceinline__ void storeQ(unsigned* __restrict__ cbase, const f32x16& A,
                                       float inv, int rt, int ct, int h, int l31) {
#pragma unroll
    for (int g = 0; g < 4; ++g)
#pragma unroll
        for (int pp = 0; pp < 2; ++pp) {
            const int reg = 4 * g + 2 * pp;
            unsigned u = pk_bf16(A[reg] * inv, A[reg + 1] * inv);
            const int rw = 32 * rt + 2 * pp + 8 * g + 4 * h;
            cbase[(rw >> 1) * 64 + 32 * ct + l31] = u;
        }
}

#define MKB1(BD, S, q, eo)                                                \
  {                                                                       \
    float4 _e0 = *(const float4*)(ep + (eo));                             \
    float4 _e1 = *(const float4*)(ep + (eo) + 8);                         \
    unsigned _u0 = pk_bf16(S[(q)+0]*_e0.x, S[(q)+1]*_e0.y);               \
    unsigned _u1 = pk_bf16(S[(q)+2]*_e0.z, S[(q)+3]*_e0.w);               \
    unsigned _u2 = pk_bf16(S[(q)+4]*_e1.x, S[(q)+5]*_e1.y);               \
    unsigned _u3 = pk_bf16(S[(q)+6]*_e1.z, S[(q)+7]*_e1.w);               \
    BD = mk8(_u0, _u1, _u2, _u3);                                         \
  }

__global__ __launch_bounds__(128, 3) void scan_kernel(
    const float* __restrict__ trans, const float* __restrict__ logits,
    unsigned* __restrict__ Cpk, float* __restrict__ S2tab)
{
    const int j = blockIdx.x;          // chunk
    const int b = blockIdx.y;          // batch
    const int tid = threadIdx.x;
    const int ct = tid >> 6;           // wave = column half
    const int lane = tid & 63;
    const int h = lane >> 5, l31 = lane & 31;
    const int t0 = j * 32;
    const int cl = (j == NCHUNK - 1) ? 31 : 32;

    __shared__ __align__(16) float El[32 * ELD];
    __shared__ float mxs[2], svs[2];

    // ---- stage E rows (4 lanes per row, 12 cols each), row-max normalized ----
    const int row = tid >> 2, cs = tid & 3;
    float s2v = 0.f;
    {
        float e[12];
        float mloc = -3.0e38f;
        if (row < cl) {
            const float* lr = logits + ((size_t)b * NT + t0 + 1 + row) * NC + cs * 12;
            float4 v0 = *(const float4*)(lr + 0);
            float4 v1 = *(const float4*)(lr + 4);
            float4 v2 = *(const float4*)(lr + 8);
            e[0]=v0.x; e[1]=v0.y; e[2]=v0.z;  e[3]=v0.w;
            e[4]=v1.x; e[5]=v1.y; e[6]=v1.z;  e[7]=v1.w;
            e[8]=v2.x; e[9]=v2.y; e[10]=v2.z; e[11]=v2.w;
#pragma unroll
            for (int q = 0; q < 12; ++q) mloc = fmaxf(mloc, e[q]);
        }
        mloc = fmaxf(mloc, __shfl_xor(mloc, 1));
        mloc = fmaxf(mloc, __shfl_xor(mloc, 2));
        const float m2 = mloc * L2E;
        float* er = El + row * ELD;
        if (row < cl) {
#pragma unroll
            for (int q = 0; q < 12; ++q) er[cs * 12 + q] = exp2f(e[q] * L2E - m2);
            if (cs == 0) s2v = m2;
        }
        if (cs == 3) {   // zero-pad cols 48..67 (kills k>=48 + NaN-safety)
            *(float4*)(er + 48) = make_float4(0.f, 0.f, 0.f, 0.f);
            *(float4*)(er + 52) = make_float4(0.f, 0.f, 0.f, 0.f);
            *(float4*)(er + 56) = make_float4(0.f, 0.f, 0.f, 0.f);
            *(float4*)(er + 60) = make_float4(0.f, 0.f, 0.f, 0.f);
            *(float4*)(er + 64) = make_float4(0.f, 0.f, 0.f, 0.f);
        }
    }
    __syncthreads();

    // ---- constant A = P^T frags; acc init = own column half of P^T ----
    bf16x8 A00 = mkA(trans, l31,      h, 0), A01 = mkA(trans, l31,      h, 1),
           A02 = mkA(trans, l31,      h, 2), A03 = mkA(trans, l31,      h, 3);
    bf16x8 A10 = mkA(trans, l31 + 32, h, 0), A11 = mkA(trans, l31 + 32, h, 1),
           A12 = mkA(trans, l31 + 32, h, 2), A13 = mkA(trans, l31 + 32, h, 3);

    f32x16 acc0 = mkW(trans, 0, ct, h, l31);
    f32x16 acc1 = mkW(trans, 1, ct, h, l31);

    const int nst = cl - 1;   // 31 or 30
#pragma unroll 2
    for (int s = 1; s <= nst; ++s) {
        if (s == 16) {   // static range shift (validated in r3)
#pragma unroll
            for (int r = 0; r < 16; ++r) { acc0[r] *= 0x1p-88f; acc1[r] *= 0x1p-88f; }
        }
        const float* ep = El + (s - 1) * ELD;
        bf16x8 B0, B1, B2, B3;
        MKB1(B0, acc0, 0,  0 + 4 * h);
        MKB1(B1, acc0, 8, 16 + 4 * h);
        MKB1(B2, acc1, 0, 32 + 4 * h);
        MKB1(B3, acc1, 8, 48 + 4 * h);
        f32x16 n0 = mm4(A00, A01, A02, A03, B0, B1, B2, B3);
        f32x16 n1 = mm4(A10, A11, A12, A13, B0, B1, B2, B3);
        acc0 = n0; acc1 = n1;
    }

    // final row-scale by E_{t0+cl} (row nst)
    const float* ef = El + nst * ELD;
    scaleRows(acc0, ef, 0, h);
    scaleRows(acc1, ef, 1, h);

    // block max (cross-wave via LDS) + per-row scale sum
    float m = acc0[0];
#pragma unroll
    for (int r = 0; r < 16; ++r) { m = fmaxf(m, acc0[r]); m = fmaxf(m, acc1[r]); }
#pragma unroll
    for (int o = 32; o; o >>= 1) m = fmaxf(m, __shfl_xor(m, o));
    float sv = s2v;
#pragma unroll
    for (int o = 32; o; o >>= 1) sv += __shfl_xor(sv, o);
    if (lane == 0) { mxs[ct] = m; svs[ct] = sv; }
    __syncthreads();
    m = fmaxf(mxs[0], mxs[1]);
    const float inv = 1.f / m;

    unsigned* cbase = Cpk + (((size_t)b * NCHUNK + j) << 11);
    storeQ(cbase, acc0, inv, 0, ct, h, l31);
    storeQ(cbase, acc1, inv, 1, ct, h, l31);

    if (tid == 0) S2tab[b * NCHUNK + j] = svs[0] + svs[1] + 88.f + log2f(m);
}

// ---------------------------------------------------------------------------
// Kernel 3: combine — a <- C_j a over 32 chunks; a broadcast via LDS
// (1 ds_write + 12 wave-uniform ds_read_b128 per step), dbuf C loads.
// ---------------------------------------------------------------------------
__device__ __forceinline__ void comb_load(const unsigned* __restrict__ cb, int k,
                                          uint4* __restrict__ buf) {
    const uint4* p = (const uint4*)(cb + (size_t)k * 2048);
#pragma unroll
    for (int q = 0; q < 12; ++q) buf[q] = p[q];
}

__device__ __forceinline__ void comb_step(const uint4* __restrict__ buf,
                                          float& a, unsigned sh,
                                          float* __restrict__ ash, int lane) {
    ash[lane] = a;
    __syncthreads();
    float4 av[12];
#pragma unroll
    for (int q = 0; q < 12; ++q) av[q] = *(const float4*)(ash + 4 * q);
    float a0 = 0.f, a1 = 0.f, a2 = 0.f, a3 = 0.f;
#pragma unroll
    for (int q = 0; q < 12; ++q) {
        uint4 u = buf[q];
        a0 = fmaf(__uint_as_float((u.x << sh) & 0xffff0000u), av[q].x, a0);
        a1 = fmaf(__uint_as_float((u.y << sh) & 0xffff0000u), av[q].y, a1);
        a2 = fmaf(__uint_as_float((u.z << sh) & 0xffff0000u), av[q].z, a2);
        a3 = fmaf(__uint_as_float((u.w << sh) & 0xffff0000u), av[q].w, a3);
    }
    a = (a0 + a1) + (a2 + a3);
    __syncthreads();
}

__global__ __launch_bounds__(64) void combine_kernel(
    const int* __restrict__ labels, const float* __restrict__ logits,
    const float* __restrict__ start_t, const float* __restrict__ end_t,
    const float* __restrict__ trans, const unsigned* __restrict__ Cpk,
    const float* __restrict__ S2tab, float* __restrict__ out_scalar)
{
    __shared__ __align__(16) float ash[64];
    const int b = blockIdx.x;
    const int lane = threadIdx.x;
    const int* __restrict__ lab = labels + b * NT;
    const float* __restrict__ lgp = logits + (size_t)b * NT * NC;

    // numerator
    float nsum = 0.f;
#pragma unroll
    for (int i = 0; i < NT / 64; ++i) {
        const int t = i * 64 + lane;
        const int l = lab[t];
        nsum += lgp[t * NC + l];
        if (t > 0) nsum += trans[lab[t - 1] * NC + l];
    }
#pragma unroll
    for (int o = 32; o; o >>= 1) nsum += __shfl_xor(nsum, o);

    // forward: a0, then 32 chunk matvecs
    float a = (lane < NC) ? exp2f((start_t[lane] + lgp[lane]) * L2E) : 0.f;
    float S2 = 0.f;
    const unsigned sh = (lane & 1) ? 0u : 16u;
    const unsigned* cb = Cpk + (((size_t)b * NCHUNK) << 11) + (lane >> 1) * 64;

    uint4 bufA[12], bufB[12];
    comb_load(cb, 0, bufA);
#pragma unroll 1
    for (int k = 0; k < NCHUNK; k += 2) {
        if (k + 1 < NCHUNK) comb_load(cb, k + 1, bufB);
        comb_step(bufA, a, sh, ash, lane);
        if (k + 2 < NCHUNK) comb_load(cb, k + 2, bufA);
        comb_step(bufB, a, sh, ash, lane);
        if ((k & 7) == 6) {   // rescale every 8 chunk-steps
            float mm = a;
#pragma unroll
            for (int o = 32; o; o >>= 1) mm = fmaxf(mm, __shfl_xor(mm, o));
            a *= 1.f / mm;
            S2 += log2f(mm);
        }
    }

    float pe = (lane < NC) ? a * exp2f(end_t[lane] * L2E) : 0.f;
#pragma unroll
    for (int o = 32; o; o >>= 1) pe += __shfl_xor(pe, o);
    float s2k = (lane < NCHUNK) ? S2tab[b * NCHUNK + lane] : 0.f;
#pragma unroll
    for (int o = 32; o; o >>= 1) s2k += __shfl_xor(s2k, o);

    if (lane == 0) {
        const float logz = (S2 + s2k + log2f(pe)) * LN2;
        const float numer = nsum + start_t[lab[0]] + end_t[lab[NT - 1]];
        atomicAdd(out_scalar, logz - numer);
    }
}

// ---------------------------------------------------------------------------
extern "C" void kernel_launch(void* const* d_in, const int* in_sizes, int n_in,
                              void* d_out, int out_size, void* d_ws, size_t ws_size,
                              hipStream_t stream) {
    const int*   x       = (const int*)d_in[0];
    const int*   labels  = (const int*)d_in[1];
    const float* emb     = (const float*)d_in[2];
    const float* fc_w    = (const float*)d_in[3];
    const float* fc_b    = (const float*)d_in[4];
    const float* start_t = (const float*)d_in[5];
    const float* end_t   = (const float*)d_in[6];
    const float* trans   = (const float*)d_in[7];

    float* out = (float*)d_out;
    float* out_scalar = out + (size_t)NB * NT * NC;

    char* ws = (char*)d_ws;
    constexpr size_t CP_BYTES = (size_t)NB * NCHUNK * 2048 * 4;   // 16 MB
    unsigned* Cpk   = (unsigned*)ws;
    float*    S2tab = (float*)(ws + CP_BYTES);

    (void)hipMemsetAsync(out_scalar, 0, sizeof(float), stream);
    logits_kernel<<<NB * NT / 64, 128, 0, stream>>>(x, emb, fc_w, fc_b, out);
    scan_kernel<<<dim3(NCHUNK, NB), 128, 0, stream>>>(trans, out, Cpk, S2tab);
    combine_kernel<<<NB, 64, 0, stream>>>(labels, out, start_t, end_t, trans, Cpk, S2tab, out_scalar);
}

// Round 7
// 91.019 us; speedup vs baseline: 1.4779x; 1.0301x over previous
//
#include <hip/hip_runtime.h>
#include <hip/hip_bf16.h>
#include <math.h>

#define NV 50257
#define NE 256
#define NC 48
#define NB 64
#define NT 1024
#define NCHUNK 32          // 31 chunks x 32 factors + 1 chunk x 31 = 1023
#define ELD 68             // El row stride (floats)
#define L2E 1.44269504088896340736f
#define LN2 0.69314718055994530942f

typedef __attribute__((ext_vector_type(8)))  short bf16x8;
typedef __attribute__((ext_vector_type(16))) float f32x16;

__device__ __forceinline__ unsigned pk_bf16(float lo, float hi) {
    unsigned r;
    asm("v_cvt_pk_bf16_f32 %0, %1, %2" : "=v"(r) : "v"(lo), "v"(hi));
    return r;
}
__device__ __forceinline__ bf16x8 mk8(unsigned u0, unsigned u1, unsigned u2, unsigned u3) {
    union { unsigned u[4]; bf16x8 v; } t;
    t.u[0] = u0; t.u[1] = u1; t.u[2] = u2; t.u[3] = u3;
    return t.v;
}

// ---------------------------------------------------------------------------
// Kernel 1: logits[b,t,c] = emb[x[b,t]] . fc_w[c] + fc_b[c]   (pure GEMM)
// Also zeroes out_scalar (block 0) so no host-side memset is needed.
// ---------------------------------------------------------------------------
#define PREF(BUF, CH)                                                     \
  { _Pragma("unroll")                                                     \
    for (int i_ = 0; i_ < 4; ++i_) {                                      \
        BUF[2*i_]   = r4[i_][(CH)*2];                                     \
        BUF[2*i_+1] = r4[i_][(CH)*2+1];                                   \
    } }

#define COMP(BUF, CH)                                                     \
  { _Pragma("unroll")                                                     \
    for (int jc_ = 0; jc_ < 12; ++jc_) {                                  \
        const float* wp_ = ws + (cg*12+jc_)*260 + wv*128 + (CH)*8;        \
        float4 w0_ = *(const float4*)(wp_);                               \
        float4 w1_ = *(const float4*)(wp_+4);                             \
        _Pragma("unroll")                                                 \
        for (int i_ = 0; i_ < 4; ++i_) {                                  \
            acc[i_][jc_] = fmaf(BUF[2*i_].x,   w0_.x, acc[i_][jc_]);      \
            acc[i_][jc_] = fmaf(BUF[2*i_].y,   w0_.y, acc[i_][jc_]);      \
            acc[i_][jc_] = fmaf(BUF[2*i_].z,   w0_.z, acc[i_][jc_]);      \
            acc[i_][jc_] = fmaf(BUF[2*i_].w,   w0_.w, acc[i_][jc_]);      \
            acc[i_][jc_] = fmaf(BUF[2*i_+1].x, w1_.x, acc[i_][jc_]);      \
            acc[i_][jc_] = fmaf(BUF[2*i_+1].y, w1_.y, acc[i_][jc_]);      \
            acc[i_][jc_] = fmaf(BUF[2*i_+1].z, w1_.z, acc[i_][jc_]);      \
            acc[i_][jc_] = fmaf(BUF[2*i_+1].w, w1_.w, acc[i_][jc_]);      \
        } } }

__global__ __launch_bounds__(128) void logits_kernel(
    const int* __restrict__ x, const float* __restrict__ emb,
    const float* __restrict__ w, const float* __restrict__ bias,
    float* __restrict__ out, float* __restrict__ out_scalar)
{
    __shared__ __align__(16) float ws[NC * 260];
    __shared__ __align__(16) float red[64 * NC];
    __shared__ float bsh[NC];

    const int tid = threadIdx.x;
    const int base = blockIdx.x * 64;

    if (blockIdx.x == 0 && tid == 0) *out_scalar = 0.f;

#pragma unroll
    for (int i = 0; i < 24; ++i) {
        const int q = i * 128 + tid;
        const int c = q >> 6, kq = q & 63;
        float4 v = ((const float4*)w)[q];
        *(float4*)(ws + c * 260 + 4 * kq) = v;
    }
    if (tid < NC) bsh[tid] = bias[tid];

    const int wv = tid >> 6;
    const int lane = tid & 63;
    const int tg = lane >> 2, cg = lane & 3;
    const int tok0 = base + tg * 4;

    const float4* r4[4];
#pragma unroll
    for (int i = 0; i < 4; ++i)
        r4[i] = (const float4*)(emb + (size_t)x[tok0 + i] * NE) + wv * 32;

    float acc[4][12];
#pragma unroll
    for (int i = 0; i < 4; ++i)
#pragma unroll
        for (int j = 0; j < 12; ++j) acc[i][j] = 0.f;

    __syncthreads();

    float4 cur[8], nxt[8];
    PREF(cur, 0);
#pragma unroll 1
    for (int chp = 0; chp < 8; ++chp) {
        const int ch0 = 2 * chp;
        PREF(nxt, ch0 + 1);
        COMP(cur, ch0);
        if (chp < 7) PREF(cur, ch0 + 2);
        COMP(nxt, ch0 + 1);
    }

    if (wv == 1) {
#pragma unroll
        for (int i = 0; i < 4; ++i) {
            float* rp = red + (tg * 4 + i) * NC + cg * 12;
            *(float4*)(rp + 0) = make_float4(acc[i][0], acc[i][1], acc[i][2], acc[i][3]);
            *(float4*)(rp + 4) = make_float4(acc[i][4], acc[i][5], acc[i][6], acc[i][7]);
            *(float4*)(rp + 8) = make_float4(acc[i][8], acc[i][9], acc[i][10], acc[i][11]);
        }
    }
    __syncthreads();
    if (wv == 0) {
#pragma unroll
        for (int i = 0; i < 4; ++i) {
            const float* rp = red + (tg * 4 + i) * NC + cg * 12;
            float4 p0 = *(const float4*)(rp + 0);
            float4 p1 = *(const float4*)(rp + 4);
            float4 p2 = *(const float4*)(rp + 8);
            float* op = out + (size_t)(base + tg * 4 + i) * NC + cg * 12;
            *(float4*)(op + 0) = make_float4(acc[i][0] + p0.x + bsh[cg*12+0], acc[i][1] + p0.y + bsh[cg*12+1],
                                             acc[i][2] + p0.z + bsh[cg*12+2], acc[i][3] + p0.w + bsh[cg*12+3]);
            *(float4*)(op + 4) = make_float4(acc[i][4] + p1.x + bsh[cg*12+4], acc[i][5] + p1.y + bsh[cg*12+5],
                                             acc[i][6] + p1.z + bsh[cg*12+6], acc[i][7] + p1.w + bsh[cg*12+7]);
            *(float4*)(op + 8) = make_float4(acc[i][8] + p2.x + bsh[cg*12+8], acc[i][9] + p2.y + bsh[cg*12+9],
                                             acc[i][10] + p2.z + bsh[cg*12+10], acc[i][11] + p2.w + bsh[cg*12+11]);
        }
    }
}

// ---------------------------------------------------------------------------
// Kernel 2: chunked matrix scan — column-split, inline-asm MFMA:
//   D/C pinned to arch VGPRs ("+v"), A-frags pinned to AGPRs ("a").
// ---------------------------------------------------------------------------
__device__ __forceinline__ bf16x8 mkA(const float* __restrict__ trans, int r, int h, int kf) {
    unsigned u[4];
#pragma unroll
    for (int p = 0; p < 4; ++p) {
        const int i0 = 2 * p;
        const int k0 = 16 * kf + 4 * h + (i0 & 3) + 8 * (i0 >> 2);
        const int k1 = k0 + 1;
        float v0 = (r < NC && k0 < NC) ? exp2f(trans[k0 * NC + r] * L2E) : 0.f;
        float v1 = (r < NC && k1 < NC) ? exp2f(trans[k1 * NC + r] * L2E) : 0.f;
        u[p] = pk_bf16(v0, v1);
    }
    return mk8(u[0], u[1], u[2], u[3]);
}

__device__ __forceinline__ f32x16 mkW(const float* __restrict__ trans, int rt, int ct, int h, int l31) {
    f32x16 r;
#pragma unroll
    for (int reg = 0; reg < 16; ++reg) {
        const int rw = 32 * rt + (reg & 3) + 8 * (reg >> 2) + 4 * h;
        const int cc = 32 * ct + l31;
        r[reg] = (rw < NC && cc < NC) ? exp2f(trans[cc * NC + rw] * L2E) : 0.f;
    }
    return r;
}

__device__ __forceinline__ f32x16 mm4(bf16x8 a0, bf16x8 a1, bf16x8 a2, bf16x8 a3,
                                      bf16x8 b0, bf16x8 b1, bf16x8 b2, bf16x8 b3,
                                      const f32x16& z) {
    f32x16 d;
    asm("v_mfma_f32_32x32x16_bf16 %0, %1, %2, %3"
        : "=v"(d) : "a"(a0), "v"(b0), "v"(z));
    asm("v_mfma_f32_32x32x16_bf16 %0, %1, %2, %0"
        : "+v"(d) : "a"(a1), "v"(b1));
    asm("v_mfma_f32_32x32x16_bf16 %0, %1, %2, %0"
        : "+v"(d) : "a"(a2), "v"(b2));
    asm("v_mfma_f32_32x32x16_bf16 %0, %1, %2, %0"
        : "+v"(d) : "a"(a3), "v"(b3));
    return d;
}

__device__ __forceinline__ void scaleRows(f32x16& A, const float* ef, int rt, int h) {
#pragma unroll
    for (int g = 0; g < 4; ++g) {
        float4 e = *(const float4*)(ef + 32 * rt + 8 * g + 4 * h);
        A[4*g+0] *= e.x; A[4*g+1] *= e.y; A[4*g+2] *= e.z; A[4*g+3] *= e.w;
    }
}

__device__ __forceinline__ void storeQ(unsigned* __restrict__ cbase, const f32x16& A,
                                       float inv, int rt, int ct, int h, int l31) {
#pragma unroll
    for (int g = 0; g < 4; ++g)
#pragma unroll
        for (int pp = 0; pp < 2; ++pp) {
            const int reg = 4 * g + 2 * pp;
            unsigned u = pk_bf16(A[reg] * inv, A[reg + 1] * inv);
            const int rw = 32 * rt + 2 * pp + 8 * g + 4 * h;
            cbase[(rw >> 1) * 64 + 32 * ct + l31] = u;
        }
}

#define MKB1(BD, S, q, eo)                                                \
  {                                                                       \
    float4 _e0 = *(const float4*)(ep + (eo));                             \
    float4 _e1 = *(const float4*)(ep + (eo) + 8);                         \
    unsigned _u0 = pk_bf16(S[(q)+0]*_e0.x, S[(q)+1]*_e0.y);               \
    unsigned _u1 = pk_bf16(S[(q)+2]*_e0.z, S[(q)+3]*_e0.w);               \
    unsigned _u2 = pk_bf16(S[(q)+4]*_e1.x, S[(q)+5]*_e1.y);               \
    unsigned _u3 = pk_bf16(S[(q)+6]*_e1.z, S[(q)+7]*_e1.w);               \
    BD = mk8(_u0, _u1, _u2, _u3);                                         \
  }

__global__ __launch_bounds__(128, 3) void scan_kernel(
    const float* __restrict__ trans, const float* __restrict__ logits,
    unsigned* __restrict__ Cpk, float* __restrict__ S2tab)
{
    const int j = blockIdx.x;          // chunk
    const int b = blockIdx.y;          // batch
    const int tid = threadIdx.x;
    const int ct = tid >> 6;           // wave = column half
    const int lane = tid & 63;
    const int h = lane >> 5, l31 = lane & 31;
    const int t0 = j * 32;
    const int cl = (j == NCHUNK - 1) ? 31 : 32;

    __shared__ __align__(16) float El[32 * ELD];
    __shared__ float mxs[2], svs[2];

    // ---- stage E rows (4 lanes per row, 12 cols each), row-max normalized ----
    const int row = tid >> 2, cs = tid & 3;
    float s2v = 0.f;
    {
        float e[12];
        float mloc = -3.0e38f;
        if (row < cl) {
            const float* lr = logits + ((size_t)b * NT + t0 + 1 + row) * NC + cs * 12;
            float4 v0 = *(const float4*)(lr + 0);
            float4 v1 = *(const float4*)(lr + 4);
            float4 v2 = *(const float4*)(lr + 8);
            e[0]=v0.x; e[1]=v0.y; e[2]=v0.z;  e[3]=v0.w;
            e[4]=v1.x; e[5]=v1.y; e[6]=v1.z;  e[7]=v1.w;
            e[8]=v2.x; e[9]=v2.y; e[10]=v2.z; e[11]=v2.w;
#pragma unroll
            for (int q = 0; q < 12; ++q) mloc = fmaxf(mloc, e[q]);
        }
        mloc = fmaxf(mloc, __shfl_xor(mloc, 1));
        mloc = fmaxf(mloc, __shfl_xor(mloc, 2));
        const float m2 = mloc * L2E;
        float* er = El + row * ELD;
        if (row < cl) {
#pragma unroll
            for (int q = 0; q < 12; ++q) er[cs * 12 + q] = exp2f(e[q] * L2E - m2);
            if (cs == 0) s2v = m2;
        }
        if (cs == 3) {
            *(float4*)(er + 48) = make_float4(0.f, 0.f, 0.f, 0.f);
            *(float4*)(er + 52) = make_float4(0.f, 0.f, 0.f, 0.f);
            *(float4*)(er + 56) = make_float4(0.f, 0.f, 0.f, 0.f);
            *(float4*)(er + 60) = make_float4(0.f, 0.f, 0.f, 0.f);
            *(float4*)(er + 64) = make_float4(0.f, 0.f, 0.f, 0.f);
        }
    }
    __syncthreads();

    // ---- constant A = P^T frags (AGPR); acc init = own column half of P^T ----
    bf16x8 A00 = mkA(trans, l31,      h, 0), A01 = mkA(trans, l31,      h, 1),
           A02 = mkA(trans, l31,      h, 2), A03 = mkA(trans, l31,      h, 3);
    bf16x8 A10 = mkA(trans, l31 + 32, h, 0), A11 = mkA(trans, l31 + 32, h, 1),
           A12 = mkA(trans, l31 + 32, h, 2), A13 = mkA(trans, l31 + 32, h, 3);

    f32x16 acc0 = mkW(trans, 0, ct, h, l31);
    f32x16 acc1 = mkW(trans, 1, ct, h, l31);

    f32x16 z;
#pragma unroll
    for (int i = 0; i < 16; ++i) z[i] = 0.f;

    const int nst = cl - 1;   // 31 or 30
#pragma unroll 1
    for (int s = 1; s <= nst; ++s) {
        if (s == 16) {   // static range shift (validated in r3)
#pragma unroll
            for (int r = 0; r < 16; ++r) { acc0[r] *= 0x1p-88f; acc1[r] *= 0x1p-88f; }
        }
        const float* ep = El + (s - 1) * ELD;
        bf16x8 B0, B1, B2, B3;
        MKB1(B0, acc0, 0,  0 + 4 * h);
        MKB1(B1, acc0, 8, 16 + 4 * h);
        MKB1(B2, acc1, 0, 32 + 4 * h);
        MKB1(B3, acc1, 8, 48 + 4 * h);
        f32x16 n0 = mm4(A00, A01, A02, A03, B0, B1, B2, B3, z);
        f32x16 n1 = mm4(A10, A11, A12, A13, B0, B1, B2, B3, z);
        acc0 = n0; acc1 = n1;
    }

    // final row-scale by E_{t0+cl} (row nst)
    const float* ef = El + nst * ELD;
    scaleRows(acc0, ef, 0, h);
    scaleRows(acc1, ef, 1, h);

    // block max (cross-wave via LDS) + per-row scale sum
    float m = acc0[0];
#pragma unroll
    for (int r = 0; r < 16; ++r) { m = fmaxf(m, acc0[r]); m = fmaxf(m, acc1[r]); }
#pragma unroll
    for (int o = 32; o; o >>= 1) m = fmaxf(m, __shfl_xor(m, o));
    float sv = s2v;
#pragma unroll
    for (int o = 32; o; o >>= 1) sv += __shfl_xor(sv, o);
    if (lane == 0) { mxs[ct] = m; svs[ct] = sv; }
    __syncthreads();
    m = fmaxf(mxs[0], mxs[1]);
    const float inv = 1.f / m;

    unsigned* cbase = Cpk + (((size_t)b * NCHUNK + j) << 11);
    storeQ(cbase, acc0, inv, 0, ct, h, l31);
    storeQ(cbase, acc1, inv, 1, ct, h, l31);

    if (tid == 0) S2tab[b * NCHUNK + j] = svs[0] + svs[1] + 88.f + log2f(m);
}

// ---------------------------------------------------------------------------
// Kernel 3: combine — a <- C_j a over 32 chunks; a broadcast via LDS.
// ---------------------------------------------------------------------------
__device__ __forceinline__ void comb_load(const unsigned* __restrict__ cb, int k,
                                          uint4* __restrict__ buf) {
    const uint4* p = (const uint4*)(cb + (size_t)k * 2048);
#pragma unroll
    for (int q = 0; q < 12; ++q) buf[q] = p[q];
}

__device__ __forceinline__ void comb_step(const uint4* __restrict__ buf,
                                          float& a, unsigned sh,
                                          float* __restrict__ ash, int lane) {
    ash[lane] = a;
    __syncthreads();
    float4 av[12];
#pragma unroll
    for (int q = 0; q < 12; ++q) av[q] = *(const float4*)(ash + 4 * q);
    float a0 = 0.f, a1 = 0.f, a2 = 0.f, a3 = 0.f;
#pragma unroll
    for (int q = 0; q < 12; ++q) {
        uint4 u = buf[q];
        a0 = fmaf(__uint_as_float((u.x << sh) & 0xffff0000u), av[q].x, a0);
        a1 = fmaf(__uint_as_float((u.y << sh) & 0xffff0000u), av[q].y, a1);
        a2 = fmaf(__uint_as_float((u.z << sh) & 0xffff0000u), av[q].z, a2);
        a3 = fmaf(__uint_as_float((u.w << sh) & 0xffff0000u), av[q].w, a3);
    }
    a = (a0 + a1) + (a2 + a3);
    __syncthreads();
}

__global__ __launch_bounds__(64) void combine_kernel(
    const int* __restrict__ labels, const float* __restrict__ logits,
    const float* __restrict__ start_t, const float* __restrict__ end_t,
    const float* __restrict__ trans, const unsigned* __restrict__ Cpk,
    const float* __restrict__ S2tab, float* __restrict__ out_scalar)
{
    __shared__ __align__(16) float ash[64];
    const int b = blockIdx.x;
    const int lane = threadIdx.x;
    const int* __restrict__ lab = labels + b * NT;
    const float* __restrict__ lgp = logits + (size_t)b * NT * NC;

    // numerator
    float nsum = 0.f;
#pragma unroll
    for (int i = 0; i < NT / 64; ++i) {
        const int t = i * 64 + lane;
        const int l = lab[t];
        nsum += lgp[t * NC + l];
        if (t > 0) nsum += trans[lab[t - 1] * NC + l];
    }
#pragma unroll
    for (int o = 32; o; o >>= 1) nsum += __shfl_xor(nsum, o);

    // forward: a0, then 32 chunk matvecs
    float a = (lane < NC) ? exp2f((start_t[lane] + lgp[lane]) * L2E) : 0.f;
    float S2 = 0.f;
    const unsigned sh = (lane & 1) ? 0u : 16u;
    const unsigned* cb = Cpk + (((size_t)b * NCHUNK) << 11) + (lane >> 1) * 64;

    uint4 bufA[12], bufB[12];
    comb_load(cb, 0, bufA);
#pragma unroll 1
    for (int k = 0; k < NCHUNK; k += 2) {
        if (k + 1 < NCHUNK) comb_load(cb, k + 1, bufB);
        comb_step(bufA, a, sh, ash, lane);
        if (k + 2 < NCHUNK) comb_load(cb, k + 2, bufA);
        comb_step(bufB, a, sh, ash, lane);
        if ((k & 7) == 6) {   // rescale every 8 chunk-steps
            float mm = a;
#pragma unroll
            for (int o = 32; o; o >>= 1) mm = fmaxf(mm, __shfl_xor(mm, o));
            a *= 1.f / mm;
            S2 += log2f(mm);
        }
    }

    float pe = (lane < NC) ? a * exp2f(end_t[lane] * L2E) : 0.f;
#pragma unroll
    for (int o = 32; o; o >>= 1) pe += __shfl_xor(pe, o);
    float s2k = (lane < NCHUNK) ? S2tab[b * NCHUNK + lane] : 0.f;
#pragma unroll
    for (int o = 32; o; o >>= 1) s2k += __shfl_xor(s2k, o);

    if (lane == 0) {
        const float logz = (S2 + s2k + log2f(pe)) * LN2;
        const float numer = nsum + start_t[lab[0]] + end_t[lab[NT - 1]];
        atomicAdd(out_scalar, logz - numer);
    }
}

// ---------------------------------------------------------------------------
extern "C" void kernel_launch(void* const* d_in, const int* in_sizes, int n_in,
                              void* d_out, int out_size, void* d_ws, size_t ws_size,
                              hipStream_t stream) {
    const int*   x       = (const int*)d_in[0];
    const int*   labels  = (const int*)d_in[1];
    const float* emb     = (const float*)d_in[2];
    const float* fc_w    = (const float*)d_in[3];
    const float* fc_b    = (const float*)d_in[4];
    const float* start_t = (const float*)d_in[5];
    const float* end_t   = (const float*)d_in[6];
    const float* trans   = (const float*)d_in[7];

    float* out = (float*)d_out;
    float* out_scalar = out + (size_t)NB * NT * NC;

    char* ws = (char*)d_ws;
    constexpr size_t CP_BYTES = (size_t)NB * NCHUNK * 2048 * 4;   // 16 MB
    unsigned* Cpk   = (unsigned*)ws;
    float*    S2tab = (float*)(ws + CP_BYTES);

    logits_kernel<<<NB * NT / 64, 128, 0, stream>>>(x, emb, fc_w, fc_b, out, out_scalar);
    scan_kernel<<<dim3(NCHUNK, NB), 128, 0, stream>>>(trans, out, Cpk, S2tab);
    combine_kernel<<<NB, 64, 0, stream>>>(labels, out, start_t, end_t, trans, Cpk, S2tab, out_scalar);
}